// Round 2
// baseline (243.615 us; speedup 1.0000x reference)
//
#include <hip/hip_runtime.h>
#include <hip/hip_bf16.h>

typedef __attribute__((ext_vector_type(8))) short short8;   // 8 bf16 (4 VGPRs) MFMA frag
typedef __attribute__((ext_vector_type(4))) short short4v;
typedef __attribute__((ext_vector_type(4))) float f32x4;

#define Bb 64
#define Cc 64
#define Tt 32
#define Nn 64
#define Kk 3
#define PITCH 72                      // u16 row pitch: 16B-aligned, bank stride 4 (<=2-way = free)
#define OUT_A_OFF 8388608L            // B*C*T*N floats of x_out, then A copy

__device__ __forceinline__ short f2bf(float f) {
    __hip_bfloat16 h = __float2bfloat16(f);
    return *reinterpret_cast<short*>(&h);
}

// One block per (b,t), 256 threads = 4 waves.
// step1: x1(64x64) = W @ x           (bf16 MFMA, fp32 acc)
// per k: A_norm = (A+I)*dinv*dinv^T  (fp32, from registers)
// step3: out += x1 @ A_norm          (bf16 MFMA, fp32 acc)
// fused: verbatim fp32 copy of A slab into out[OUT_A_OFF..].
__global__ __launch_bounds__(256, 4) void ctg_kernel(
    const float* __restrict__ X,
    const float* __restrict__ A,
    const float* __restrict__ W,
    const float* __restrict__ bias,
    float* __restrict__ out)
{
    __shared__ short sW [Cc * PITCH];   // W[cout][cin]        (A-op layout: contiguous k=cin)
    __shared__ short sXT[Nn * PITCH];   // x^T[n][cin]         (B-op layout: contiguous k=cin)
    __shared__ short sX1[Cc * PITCH];   // x1[c][n]            (A-op layout: contiguous k=n)
    __shared__ short sAT[Nn * PITCH];   // A_norm^T[m][n]      (B-op layout: contiguous k=n)
    __shared__ float sDinv[Nn];
    __shared__ float sB[Cc];

    const int tid = threadIdx.x;
    const int b = blockIdx.x >> 5;      // T = 32
    const int t = blockIdx.x & 31;
    const int l  = tid & 63;
    const int w  = tid >> 6;            // wave id 0..3 -> output row stripe
    const int lr = l & 15;              // MFMA: A-row m / B-col n / C-col
    const int lq = l >> 4;              // MFMA quad

    const long xbase = (long)b * (Cc * Tt * Nn) + (long)t * Nn;   // + c*2048 + n

    // ---- stage W (bf16) and x^T (bf16) ----
    #pragma unroll
    for (int j = 0; j < 4; ++j) {
        int q  = tid + 256 * j;          // 0..1023 float4s
        int r  = q >> 4;                 // row (cout / cin)
        int c0 = (q & 15) * 4;           // col start
        f32x4 wv = *(const f32x4*)(W + r * 64 + c0);
        short4v ws;
        #pragma unroll
        for (int i = 0; i < 4; ++i) ws[i] = f2bf(wv[i]);
        *(short4v*)&sW[r * PITCH + c0] = ws;
        f32x4 xv = *(const f32x4*)(X + xbase + (long)r * (Tt * Nn) + c0);
        #pragma unroll
        for (int i = 0; i < 4; ++i) sXT[(c0 + i) * PITCH + r] = f2bf(xv[i]);
    }
    if (tid < Cc) sB[tid] = bias[tid];
    __syncthreads();

    // ---- step 1: x1 = W @ x (4 col-tiles per wave, K=64 -> 2 MFMAs each) ----
    short8 aw0 = *(const short8*)&sW[(16 * w + lr) * PITCH + 8 * lq];
    short8 aw1 = *(const short8*)&sW[(16 * w + lr) * PITCH + 32 + 8 * lq];
    f32x4 acc1[4];
    #pragma unroll
    for (int nt = 0; nt < 4; ++nt) {
        acc1[nt] = (f32x4){0.f, 0.f, 0.f, 0.f};
        short8 b0 = *(const short8*)&sXT[(16 * nt + lr) * PITCH + 8 * lq];
        short8 b1 = *(const short8*)&sXT[(16 * nt + lr) * PITCH + 32 + 8 * lq];
        acc1[nt] = __builtin_amdgcn_mfma_f32_16x16x32_bf16(aw0, b0, acc1[nt], 0, 0, 0);
        acc1[nt] = __builtin_amdgcn_mfma_f32_16x16x32_bf16(aw1, b1, acc1[nt], 0, 0, 0);
    }
    // write x1 (+bias) to LDS in A-op layout; C/D layout: row=4*lq+r, col=lr
    #pragma unroll
    for (int nt = 0; nt < 4; ++nt)
        #pragma unroll
        for (int r = 0; r < 4; ++r) {
            int c = 16 * w + 4 * lq + r;
            sX1[c * PITCH + 16 * nt + lr] = f2bf(acc1[nt][r] + sB[c]);
        }

    f32x4 acc3[4];
    #pragma unroll
    for (int mt = 0; mt < 4; ++mt) acc3[mt] = (f32x4){0.f, 0.f, 0.f, 0.f};

    const int m0 = (tid & 15) * 4;       // owned column block during normalize
    const long Abase0 = (long)b * (Kk * Tt * Nn * Nn) + (long)t * (Nn * Nn);

    for (int k = 0; k < Kk; ++k) {
        __syncthreads();   // B1: prev step3 reads of sAT done; (k=0) sX1/sXT writes published

        const long Ab = Abase0 + (long)k * (Tt * Nn * Nn);
        // coalesced load of 4096 floats; fused verbatim copy to output 1
        f32x4 av[4];
        #pragma unroll
        for (int e = 0; e < 4; ++e) av[e] = *(const f32x4*)(A + Ab + 4 * (tid + 256 * e));
        #pragma unroll
        for (int e = 0; e < 4; ++e) *(f32x4*)(out + OUT_A_OFF + Ab + 4 * (tid + 256 * e)) = av[e];

        // element (tid,e,i) is A[n = (tid>>4)+16e][m = m0+i]; row-sum via 16-lane butterfly
        float dg[4];
        #pragma unroll
        for (int e = 0; e < 4; ++e) {
            float q = av[e][0] + av[e][1] + av[e][2] + av[e][3];
            q += __shfl_xor(q, 1);
            q += __shfl_xor(q, 2);
            q += __shfl_xor(q, 4);
            q += __shfl_xor(q, 8);
            dg[e] = q;
        }
        if ((tid & 15) == 0) {
            #pragma unroll
            for (int e = 0; e < 4; ++e)
                sDinv[(tid >> 4) + 16 * e] = rsqrtf(dg[e] + 1.0f);   // deg of A+I
        }
        __syncthreads();   // B2: sDinv ready

        // normalize from registers, store transposed bf16 (B-op layout)
        float dm[4] = { sDinv[m0], sDinv[m0 + 1], sDinv[m0 + 2], sDinv[m0 + 3] };
        #pragma unroll
        for (int e = 0; e < 4; ++e) {
            int n = (tid >> 4) + 16 * e;
            float dn = sDinv[n];
            #pragma unroll
            for (int i = 0; i < 4; ++i) {
                float v = av[e][i];
                if (m0 + i == n) v += 1.0f;                          // renormalization trick: A + I
                sAT[(m0 + i) * PITCH + n] = f2bf(v * dn * dm[i]);
            }
        }
        __syncthreads();   // B3: sAT ready

        // ---- step 3: acc3 += x1 @ A_norm ----
        short8 a0 = *(const short8*)&sX1[(16 * w + lr) * PITCH + 8 * lq];
        short8 a1 = *(const short8*)&sX1[(16 * w + lr) * PITCH + 32 + 8 * lq];
        #pragma unroll
        for (int mt = 0; mt < 4; ++mt) {
            short8 b0 = *(const short8*)&sAT[(16 * mt + lr) * PITCH + 8 * lq];
            short8 b1 = *(const short8*)&sAT[(16 * mt + lr) * PITCH + 32 + 8 * lq];
            acc3[mt] = __builtin_amdgcn_mfma_f32_16x16x32_bf16(a0, b0, acc3[mt], 0, 0, 0);
            acc3[mt] = __builtin_amdgcn_mfma_f32_16x16x32_bf16(a1, b1, acc3[mt], 0, 0, 0);
        }
    }

    // ---- store x_out fp32; C/D layout row=4*lq+r (c), col=lr (m) ----
    #pragma unroll
    for (int mt = 0; mt < 4; ++mt)
        #pragma unroll
        for (int r = 0; r < 4; ++r) {
            int c = 16 * w + 4 * lq + r;
            out[xbase + (long)c * (Tt * Nn) + 16 * mt + lr] = acc3[mt][r];
        }
}

extern "C" void kernel_launch(void* const* d_in, const int* in_sizes, int n_in,
                              void* d_out, int out_size, void* d_ws, size_t ws_size,
                              hipStream_t stream) {
    const float* X    = (const float*)d_in[0];
    const float* A    = (const float*)d_in[1];
    const float* W    = (const float*)d_in[2];
    const float* bias = (const float*)d_in[3];
    float* out = (float*)d_out;
    ctg_kernel<<<dim3(Bb * Tt), dim3(256), 0, stream>>>(X, A, W, bias, out);
}